// Round 6
// baseline (3485.044 us; speedup 1.0000x reference)
//
#include <hip/hip_runtime.h>

#define NF 32
#define HDIM 256
#define SLEN 256
#define BATCH 1024

typedef float f32x4 __attribute__((ext_vector_type(4)));
typedef __bf16 bf16x8 __attribute__((ext_vector_type(8)));
typedef unsigned int u32x4 __attribute__((ext_vector_type(4)));
typedef unsigned short u16;

#define MFMA __builtin_amdgcn_mfma_f32_16x16x32_bf16

// ---- ws layout ----
// uint4 slots [0, 672KB): packed MFMA B-fragments
// bytes [1MB, 5MB):  Wt bf16 [32 f][65536 k], k = s*256 + h   (W_sig transposed)
// bytes [8MB, 40MB): hst bf16 [1024 b][256 s][256 h]
#define WHH_O 0       // 64 j * 8 t * 64 l  = 32768 slots
#define WIH_O 32768   // 64 j * 64 l        =  4096
#define WOUT_O 36864  //  2 j * 8 t * 64 l  =  1024
#define WLAT_O 37888  // 32 j * 2 t * 64 l  =  4096
#define PREP1_N 41984
#define WT_BYTE (1u << 20)
#define HST_BYTE (8u << 20)

__device__ __forceinline__ u16 f2bf(float x) {
  union { float f; unsigned int u; } v; v.f = x;
  return (u16)((v.u + 0x7FFFu + ((v.u >> 16) & 1u)) >> 16);  // RNE
}
__device__ __forceinline__ unsigned int pk2(float a, float b) {
  return (unsigned int)f2bf(a) | ((unsigned int)f2bf(b) << 16);
}
__device__ __forceinline__ float sigf(float x) {
  return __fdividef(1.0f, 1.0f + __expf(-x));
}
__device__ __forceinline__ float tanhf_(float x) {
  return 1.0f - __fdividef(2.0f, __expf(2.0f * x) + 1.0f);
}

// Pack W_hh / W_ih / W_out / W_lat into MFMA B-fragment order:
// slot(j,t,l) element e = W[n=j*16+(l&15)][k=t*32+8*(l>>4)+e]
__global__ void prep_weights(const float* __restrict__ Whh, const float* __restrict__ Wih,
                             const float* __restrict__ Wout, const float* __restrict__ Wlat,
                             uint4* __restrict__ ws) {
  int i = blockIdx.x * 256 + threadIdx.x;
  if (i >= PREP1_N) return;
  int l = i & 63;
  int c16 = l & 15, g4 = l >> 4;
  const float* src;
  if (i < WIH_O) {                       // W_hh: rowlen 256
    int t = (i >> 6) & 7, j = i >> 9;
    src = Whh + (j * 16 + c16) * 256 + t * 32 + 8 * g4;
  } else if (i < WOUT_O) {               // W_ih: rowlen 32, single k-tile
    int ii = i - WIH_O;
    int j = ii >> 6;
    src = Wih + (j * 16 + c16) * 32 + 8 * g4;
  } else if (i < WLAT_O) {               // W_out: rowlen 256
    int ii = i - WOUT_O;
    int t = (ii >> 6) & 7, j = ii >> 9;
    src = Wout + (j * 16 + c16) * 256 + t * 32 + 8 * g4;
  } else {                               // W_lat: rowlen 64, 2 k-tiles
    int ii = i - WLAT_O;
    int t = (ii >> 6) & 1, j = ii >> 7;
    src = Wlat + (j * 16 + c16) * 64 + t * 32 + 8 * g4;
  }
  uint4 P;
  P.x = pk2(src[0], src[1]);
  P.y = pk2(src[2], src[3]);
  P.z = pk2(src[4], src[5]);
  P.w = pk2(src[6], src[7]);
  ws[i] = P;
}

// Transpose W_sig [32 f][h*256+s] (f32) -> Wt [32 f][s*256+h] (bf16).
__global__ void prep_wt(const float* __restrict__ Wsig, unsigned short* __restrict__ Wt) {
  __shared__ float tile[32][257];
  int f = blockIdx.x >> 3, hb = blockIdx.x & 7;
  int tid = threadIdx.x;  // 256
  const float* src = Wsig + f * (HDIM * SLEN) + hb * 32 * 256;
#pragma unroll
  for (int i = 0; i < 32; ++i) tile[i][tid] = src[i * 256 + tid];
  __syncthreads();
  int s = tid;
  unsigned short tmp[32];
#pragma unroll
  for (int h = 0; h < 32; ++h) tmp[h] = f2bf(tile[h][s]);
  uint4* dst = (uint4*)(Wt + f * 65536 + s * 256 + hb * 32);
  const uint4* tsrc = (const uint4*)tmp;
#pragma unroll
  for (int j = 0; j < 4; ++j) dst[j] = tsrc[j];
}

// Persistent LSTM scan: 64 WGs x 16 batch rows, 8 waves, 256 steps in-WG.
// W_hh residency: per wave q0..2 pinned in VGPRs, q4,5 in LDS (all waves),
// q3,6,7 streamed from L2 in two pipelined 12-load batches.
__global__ __launch_bounds__(512, 2) void lstm_scan(
    const float* __restrict__ z, const float* __restrict__ b_lat,
    const float* __restrict__ b_ih, const float* __restrict__ b_hh,
    const float* __restrict__ b_out,
    const uint4* __restrict__ ws, unsigned short* __restrict__ hst,
    float* __restrict__ out) {
  __shared__ __align__(16) uint4 whhl[8192];              // 128KB: q=4,5 all waves
  __shared__ __align__(16) u16 hbuf[2][16][256];          // 16KB (swizzled)
  __shared__ __align__(16) u16 thbuf[16][256];            // 8KB (swizzled; z-stage at init)
  __shared__ __align__(16) u16 xbuf[2][16][32];           // 2KB

  const int tid = threadIdx.x, w = tid >> 6, l = tid & 63;
  const int c16 = l & 15, g4 = l >> 4, r0 = g4 * 4;
  const int wg = blockIdx.x;
  const int swz = (c16 & 7) << 3;

  // LDS fill: whhl[w_][qq][kt][l_] <- W_hh j=(4+qq)*8+w_
  for (int i = tid; i < 8192; i += 512) {
    int l_ = i & 63, kt = (i >> 6) & 7, qq = (i >> 9) & 1, w_ = i >> 10;
    whhl[i] = ws[WHH_O + (((4 + qq) * 8 + w_) * 8 + kt) * 64 + l_];
  }

  // pin W_hh q=0..2 fragments (96 VGPR)
  u32x4 wp[3][8];
#pragma unroll
  for (int qi = 0; qi < 3; ++qi)
#pragma unroll
    for (int kt = 0; kt < 8; ++kt)
      wp[qi][kt] = __builtin_bit_cast(u32x4, ws[WHH_O + ((qi * 8 + w) * 8 + kt) * 64 + l]);
#pragma unroll
  for (int qi = 0; qi < 3; ++qi)
#pragma unroll
    for (int kt = 0; kt < 8; ++kt)
      asm volatile("" : "+v"(wp[qi][kt]));  // keep live; not rematerializable

  float biasv[8];
#pragma unroll
  for (int q = 0; q < 8; ++q) {
    int n = (q * 8 + w) * 16 + c16;
    biasv[q] = b_ih[n] + b_hh[n];
  }
  float bo = (w < 2) ? b_out[w * 16 + c16] : 0.f;

  // ---- init: z -> thbuf (as staging), x0 = 0 ----
  for (int idx = tid; idx < 1024; idx += 512)
    thbuf[idx >> 6][idx & 63] = f2bf(z[(wg * 16 + (idx >> 6)) * 64 + (idx & 63)]);
  xbuf[0][tid >> 5][tid & 31] = 0;
  __syncthreads();

  float cst[2][4];
  {
    bf16x8 za0 = *reinterpret_cast<const bf16x8*>(&thbuf[c16][8 * g4]);
    bf16x8 za1 = *reinterpret_cast<const bf16x8*>(&thbuf[c16][32 + 8 * g4]);
    f32x4 a2[4];
#pragma unroll
    for (int q2 = 0; q2 < 4; ++q2) {
      int j = q2 * 8 + w;
      float bl = b_lat[j * 16 + c16];
      f32x4 a = {bl, bl, bl, bl};
      a = MFMA(za0, *reinterpret_cast<const bf16x8*>(ws + WLAT_O + (j * 2 + 0) * 64 + l), a, 0, 0, 0);
      a = MFMA(za1, *reinterpret_cast<const bf16x8*>(ws + WLAT_O + (j * 2 + 1) * 64 + l), a, 0, 0, 0);
      a2[q2] = a;
    }
#pragma unroll
    for (int q2 = 0; q2 < 2; ++q2) {
      int col = q2 * 128 + w * 16 + c16;
#pragma unroll
      for (int v = 0; v < 4; ++v) {
        int rr = r0 + v;
        hbuf[0][rr][col ^ ((rr & 7) << 3)] = f2bf(a2[q2][v]);
      }
    }
#pragma unroll
    for (int p = 0; p < 2; ++p)
#pragma unroll
      for (int v = 0; v < 4; ++v) cst[p][v] = a2[2 + p][v];
  }
  __syncthreads();

  const uint4* bs3 = ws + WHH_O + ((3 * 8 + w) * 8) * 64 + l;
  const uint4* bs6 = ws + WHH_O + ((6 * 8 + w) * 8) * 64 + l;
  const uint4* bs7 = ws + WHH_O + ((7 * 8 + w) * 8) * 64 + l;

  // ---- the scan ----
  for (int s = 0; s < SLEN; ++s) {
    const int pb = s & 1;
    // batch A: stream loads q3,6,7 for kt=0..3 (in flight under pinned/LDS MFMAs)
    uint4 pf[12];
#pragma unroll
    for (int kt = 0; kt < 4; ++kt) {
      pf[kt * 3 + 0] = bs3[kt * 64];
      pf[kt * 3 + 1] = bs6[kt * 64];
      pf[kt * 3 + 2] = bs7[kt * 64];
    }
    f32x4 acc[8];
#pragma unroll
    for (int q = 0; q < 8; ++q) acc[q] = (f32x4){biasv[q], biasv[q], biasv[q], biasv[q]};
    // pinned q0..2 + LDS q4,5 (40 MFMAs, no global waits)
#pragma unroll
    for (int kt = 0; kt < 8; ++kt) {
      bf16x8 afr = *reinterpret_cast<const bf16x8*>(&hbuf[pb][c16][(kt * 32 + 8 * g4) ^ swz]);
      acc[0] = MFMA(afr, __builtin_bit_cast(bf16x8, wp[0][kt]), acc[0], 0, 0, 0);
      acc[1] = MFMA(afr, __builtin_bit_cast(bf16x8, wp[1][kt]), acc[1], 0, 0, 0);
      acc[2] = MFMA(afr, __builtin_bit_cast(bf16x8, wp[2][kt]), acc[2], 0, 0, 0);
      acc[4] = MFMA(afr, *reinterpret_cast<const bf16x8*>(&whhl[((w * 2 + 0) * 8 + kt) * 64 + l]), acc[4], 0, 0, 0);
      acc[5] = MFMA(afr, *reinterpret_cast<const bf16x8*>(&whhl[((w * 2 + 1) * 8 + kt) * 64 + l]), acc[5], 0, 0, 0);
    }
    // W_ih loads (consumed after streams; in flight during batch-A consumption)
    bf16x8 wihv[8];
#pragma unroll
    for (int q = 0; q < 8; ++q)
      wihv[q] = *reinterpret_cast<const bf16x8*>(ws + WIH_O + (q * 8 + w) * 64 + l);
    // consume batch A (kt 0..3); refill slots with batch B (kt 4..7)
#pragma unroll
    for (int kt = 0; kt < 4; ++kt) {
      bf16x8 afr = *reinterpret_cast<const bf16x8*>(&hbuf[pb][c16][(kt * 32 + 8 * g4) ^ swz]);
      acc[3] = MFMA(afr, __builtin_bit_cast(bf16x8, pf[kt * 3 + 0]), acc[3], 0, 0, 0);
      acc[6] = MFMA(afr, __builtin_bit_cast(bf16x8, pf[kt * 3 + 1]), acc[6], 0, 0, 0);
      acc[7] = MFMA(afr, __builtin_bit_cast(bf16x8, pf[kt * 3 + 2]), acc[7], 0, 0, 0);
      pf[kt * 3 + 0] = bs3[(4 + kt) * 64];
      pf[kt * 3 + 1] = bs6[(4 + kt) * 64];
      pf[kt * 3 + 2] = bs7[(4 + kt) * 64];
    }
    // consume batch B
#pragma unroll
    for (int kt = 4; kt < 8; ++kt) {
      bf16x8 afr = *reinterpret_cast<const bf16x8*>(&hbuf[pb][c16][(kt * 32 + 8 * g4) ^ swz]);
      acc[3] = MFMA(afr, __builtin_bit_cast(bf16x8, pf[(kt - 4) * 3 + 0]), acc[3], 0, 0, 0);
      acc[6] = MFMA(afr, __builtin_bit_cast(bf16x8, pf[(kt - 4) * 3 + 1]), acc[6], 0, 0, 0);
      acc[7] = MFMA(afr, __builtin_bit_cast(bf16x8, pf[(kt - 4) * 3 + 2]), acc[7], 0, 0, 0);
    }
    // x @ W_ih
    bf16x8 xfr = *reinterpret_cast<const bf16x8*>(&xbuf[pb][c16][8 * g4]);
#pragma unroll
    for (int q = 0; q < 8; ++q) acc[q] = MFMA(xfr, wihv[q], acc[q], 0, 0, 0);

    // elementwise LSTM cell (f32 state in registers)
#pragma unroll
    for (int p = 0; p < 2; ++p) {
      const int hcol = p * 128 + w * 16 + c16;
#pragma unroll
      for (int v = 0; v < 4; ++v) {
        float iv = acc[0 + p][v];
        float fv = acc[2 + p][v];
        float gv = acc[4 + p][v];
        float ov = acc[6 + p][v];
        float cc = sigf(fv) * cst[p][v] + sigf(iv) * tanhf_(gv);
        cst[p][v] = cc;
        float hh = sigf(ov) * tanhf_(cc);
        float th = tanhf_(hh);
        int rr = r0 + v;
        int sc = hcol ^ ((rr & 7) << 3);
        hbuf[pb ^ 1][rr][sc] = f2bf(hh);
        thbuf[rr][sc] = f2bf(th);
      }
    }
    __syncthreads();
    // phase 3: waves 0-1: x_next = tanh(h)@W_out^T (+ mu store);
    //          waves 4-7: copy h_{s+1} -> hst (coalesced bf16)
    if (w < 2) {
      f32x4 xacc = {bo, bo, bo, bo};
#pragma unroll
      for (int t = 0; t < 8; ++t) {
        bf16x8 ta = *reinterpret_cast<const bf16x8*>(&thbuf[c16][(t * 32 + 8 * g4) ^ swz]);
        bf16x8 wov = *reinterpret_cast<const bf16x8*>(ws + WOUT_O + (w * 8 + t) * 64 + l);
        xacc = MFMA(ta, wov, xacc, 0, 0, 0);
      }
      const int f = w * 16 + c16;
#pragma unroll
      for (int v = 0; v < 4; ++v) {
        int rr = r0 + v;
        float xv = xacc[v];
        xbuf[pb ^ 1][rr][f] = f2bf(xv);
        out[(wg * 16 + rr) * (NF * SLEN) + f * SLEN + s] = xv;
      }
    } else if (w >= 4) {
      int t4 = tid - 256;
#pragma unroll
      for (int rep = 0; rep < 2; ++rep) {
        int task = t4 + rep * 256;
        int r = task >> 5;
        int h0 = (task & 31) * 8;
        uint4 d = *reinterpret_cast<const uint4*>(&hbuf[pb ^ 1][r][h0 ^ ((r & 7) << 3)]);
        *reinterpret_cast<uint4*>(hst + ((wg * 16 + r) << 16) + (s << 8) + h0) = d;
      }
    }
    __syncthreads();
  }
}

// sigma = softplus(hs_flat @ W_sig^T + b_sig)
// 256 WGs x 4 batch rows; each wave owns a 8192-wide k-chunk; LDS reduce.
__global__ __launch_bounds__(512) void sigma_gemm(
    const unsigned short* __restrict__ hst, const unsigned short* __restrict__ Wt,
    const float* __restrict__ b_sig, float* __restrict__ out) {
  __shared__ float sred[8][16][32];  // 16KB
  const int tid = threadIdx.x;
  const int w = tid >> 6;
  const int l = tid & 63;
  const int c16 = l & 15;
  const int g4 = l >> 4;
  const int wg = blockIdx.x;

  const unsigned short* ap =
      hst + (((wg << 2) + (c16 & 3)) << 16) + ((w * 32) << 8) + (g4 << 3);
  const unsigned short* bp0 = Wt + (c16 << 16) + ((w * 32) << 8) + (g4 << 3);
  const unsigned short* bp1 = Wt + ((16 + c16) << 16) + ((w * 32) << 8) + (g4 << 3);

  f32x4 a0 = {0.f, 0.f, 0.f, 0.f}, a1 = {0.f, 0.f, 0.f, 0.f};
#pragma unroll 8
  for (int kk = 0; kk < 256; ++kk) {
    int off = ((kk >> 3) << 8) + ((kk & 7) << 5);
    bf16x8 av = *reinterpret_cast<const bf16x8*>(ap + off);
    a0 = MFMA(av, *reinterpret_cast<const bf16x8*>(bp0 + off), a0, 0, 0, 0);
    a1 = MFMA(av, *reinterpret_cast<const bf16x8*>(bp1 + off), a1, 0, 0, 0);
  }
#pragma unroll
  for (int v = 0; v < 4; ++v) {
    sred[w][g4 * 4 + v][c16] = a0[v];
    sred[w][g4 * 4 + v][16 + c16] = a1[v];
  }
  __syncthreads();
  int b = tid >> 5, f = tid & 31;
  if (b < 4) {
    float acc = b_sig[f];
#pragma unroll
    for (int ww = 0; ww < 8; ++ww) acc += sred[ww][b][f];
    float sp = fmaxf(acc, 0.0f) + log1pf(__expf(-fabsf(acc)));
    out[BATCH * NF * SLEN + ((wg << 2) + b) * NF + f] = sp;
  }
}

extern "C" void kernel_launch(void* const* d_in, const int* in_sizes, int n_in,
                              void* d_out, int out_size, void* d_ws, size_t ws_size,
                              hipStream_t stream) {
  (void)in_sizes; (void)n_in; (void)out_size; (void)ws_size;
  const float* z     = (const float*)d_in[0];
  const float* W_lat = (const float*)d_in[1];
  const float* b_lat = (const float*)d_in[2];
  const float* W_ih  = (const float*)d_in[3];
  const float* b_ih  = (const float*)d_in[4];
  const float* W_hh  = (const float*)d_in[5];
  const float* b_hh  = (const float*)d_in[6];
  const float* W_out = (const float*)d_in[7];
  const float* b_out = (const float*)d_in[8];
  const float* W_sig = (const float*)d_in[9];
  const float* b_sig = (const float*)d_in[10];
  char* wsb = (char*)d_ws;
  uint4* ws = (uint4*)wsb;
  unsigned short* Wt  = (unsigned short*)(wsb + WT_BYTE);
  unsigned short* hst = (unsigned short*)(wsb + HST_BYTE);
  float* out = (float*)d_out;

  prep_weights<<<(PREP1_N + 255) / 256, 256, 0, stream>>>(W_hh, W_ih, W_out, W_lat, ws);
  prep_wt<<<256, 256, 0, stream>>>(W_sig, Wt);
  lstm_scan<<<64, 512, 0, stream>>>(z, b_lat, b_ih, b_hh, b_out, ws, hst, out);
  sigma_gemm<<<256, 512, 0, stream>>>(hst, Wt, b_sig, out);
}